// Round 1
// 393.555 us; speedup vs baseline: 1.0542x; 1.0542x over previous
//
#include <hip/hip_runtime.h>

#define BB 32
#define CC 512
#define HWN 1024
#define DD 64
#define OO 640  // 2*DD + CC

typedef short bf16x8 __attribute__((ext_vector_type(8)));
typedef float f32x4 __attribute__((ext_vector_type(4)));
typedef __attribute__((address_space(1))) const void gvoid;
typedef __attribute__((address_space(3))) void svoid;

__device__ __forceinline__ void gload_lds16(const void* g, void* l) {
    __builtin_amdgcn_global_load_lds((gvoid*)g, (svoid*)l, 16, 0, 0);
}

__device__ __forceinline__ unsigned short f2bf(float f) {
    unsigned int u = __float_as_uint(f);
    unsigned int r = u + 0x7FFFu + ((u >> 16) & 1u);  // RNE
    return (unsigned short)(r >> 16);
}
__device__ __forceinline__ float bf2f(unsigned short h) {
    return __uint_as_float(((unsigned int)h) << 16);
}

// ---------------- f32 -> bf16 convert, all 3 weight matrices in one launch ----
__global__ __launch_bounds__(256) void cvt3_kernel(const float* __restrict__ a,
                                                   const float* __restrict__ b,
                                                   const float* __restrict__ c,
                                                   unsigned short* __restrict__ oa,
                                                   unsigned short* __restrict__ ob,
                                                   unsigned short* __restrict__ oc) {
    const int n1 = OO * CC, n2 = CC * CC;
    int i = blockIdx.x * 256 + threadIdx.x;
    if (i < n1)            oa[i] = f2bf(a[i]);
    else if (i < n1 + n2)  ob[i - n1] = f2bf(b[i - n1]);
    else                   oc[i - n1 - n2] = f2bf(c[i - n1 - n2]);
}

// ---------------- BN stats: one block per channel (fp32 input, bn1 only) ------
template <bool INBF16>
__global__ __launch_bounds__(256) void bn_stats_kernel(const void* __restrict__ xv,
                                                       float* __restrict__ mean,
                                                       float* __restrict__ rstd) {
    int c = blockIdx.x;
    int t = threadIdx.x;
    float s = 0.f, s2 = 0.f;
    if (INBF16) {
        const unsigned int* x = (const unsigned int*)xv;  // 2 bf16 per uint
        for (int b = 0; b < BB; ++b) {
            const unsigned int* p = x + ((size_t)b * CC + c) * (HWN / 2);
#pragma unroll
            for (int i = 0; i < 2; ++i) {
                unsigned int w = p[t + i * 256];
                float v0 = bf2f((unsigned short)(w & 0xffffu));
                float v1 = bf2f((unsigned short)(w >> 16));
                s += v0 + v1; s2 += v0 * v0 + v1 * v1;
            }
        }
    } else {
        const float* x = (const float*)xv;
        for (int b = 0; b < BB; ++b) {
            const float* p = x + ((size_t)b * CC + c) * HWN;
#pragma unroll
            for (int i = 0; i < 4; ++i) {
                float v = p[t + i * 256];
                s += v; s2 += v * v;
            }
        }
    }
    for (int off = 32; off > 0; off >>= 1) {
        s  += __shfl_down(s,  off, 64);
        s2 += __shfl_down(s2, off, 64);
    }
    __shared__ float sh[4], sh2[4];
    int wave = t >> 6;
    if ((t & 63) == 0) { sh[wave] = s; sh2[wave] = s2; }
    __syncthreads();
    if (t == 0) {
        float ts = 0.f, ts2 = 0.f;
        for (int w = 0; w < 4; ++w) { ts += sh[w]; ts2 += sh2[w]; }
        const float invN = 1.f / (float)(BB * HWN);
        float m = ts * invN;
        float var = ts2 * invN - m * m;
        mean[c] = m;
        rstd[c] = rsqrtf(var + 1e-5f);
    }
}

// ------- BN apply + transpose: x[b][c][s] -> outT[b][s][c] bf16 (+relu) -------
template <bool RELU, bool INBF16>
__global__ __launch_bounds__(256) void bn_apply_t_kernel(const void* __restrict__ xv,
                                                         const float* __restrict__ mean,
                                                         const float* __restrict__ rstd,
                                                         const float* __restrict__ g,
                                                         const float* __restrict__ bta,
                                                         unsigned short* __restrict__ outT) {
    __shared__ float tile[64][65];
    int b  = blockIdx.z;
    int c0 = blockIdx.y * 64;
    int s0 = blockIdx.x * 64;
    int t = threadIdx.x;
    int sl = t & 63, grp = t >> 6;
#pragma unroll
    for (int i = 0; i < 16; ++i) {
        int cr = i * 4 + grp;
        int c = c0 + cr;
        float r  = rstd[c] * g[c];
        float sh = bta[c] - mean[c] * r;
        float xval;
        if (INBF16) {
            const unsigned short* xb = (const unsigned short*)xv;
            xval = bf2f(xb[((size_t)b * CC + c0 + cr) * HWN + s0 + sl]);
        } else {
            const float* xb = (const float*)xv;
            xval = xb[((size_t)b * CC + c0 + cr) * HWN + s0 + sl];
        }
        float v = fmaf(xval, r, sh);
        if (RELU) v = fmaxf(v, 0.f);
        tile[cr][sl] = v;
    }
    __syncthreads();
    unsigned short* ob = outT + ((size_t)b * HWN + s0) * CC + c0;
#pragma unroll
    for (int i = 0; i < 16; ++i) {
        int srow = i * 4 + grp;
        ob[(size_t)srow * CC + sl] = f2bf(tile[sl][srow]);
    }
}

// -------- reduce: invsum[b][k] = 1 / sum_n rowpartQ[b][n][k]  (softmax denom) --
__global__ __launch_bounds__(256) void reduce_invsum_kernel(const float* __restrict__ part,
                                                            float* __restrict__ invsum) {
    int idx = blockIdx.x * 256 + threadIdx.x;  // 32 * 1024
    int b = idx >> 10, k = idx & 1023;
    float s = 0.f;
#pragma unroll
    for (int n = 0; n < 8; ++n) s += part[(((size_t)b * 8 + n) << 10) + k];
    invsum[idx] = 1.f / s;
}

// -------- reduce: bn2 mean/rstd from per-block partial (sum, sumsq) pairs ------
// part layout: [pair p = b*8+n][2][512] -> p*1024 + {0,512} + c
__global__ __launch_bounds__(256) void reduce_bnstats_kernel(const float* __restrict__ part,
                                                             float* __restrict__ mean,
                                                             float* __restrict__ rstd) {
    int c = blockIdx.x * 256 + threadIdx.x;  // 512
    float s = 0.f, s2 = 0.f;
    for (int p = 0; p < BB * 8; ++p) {
        s  += part[(size_t)p * 1024 + c];
        s2 += part[(size_t)p * 1024 + 512 + c];
    }
    const float invN = 1.f / (float)(BB * HWN);
    float m = s * invN;
    mean[c] = m;
    rstd[c] = rsqrtf(s2 * invN - m * m + 1e-5f);
}

// ---------------- MFMA bf16 GEMM: C[b] = scale*(A @ Bt^T) (+bias)(+relu)(+resid)
// SCALEMODE: 0 none, 1 per-column scale cscale[b*strideCS + col] (applied before
//            bias/resid — deferred softmax normalization).
// ROWRED:    0 none
//            1 v = exp(v) before store; per-row sums -> rowpart[(b*NB+nb)*M + row]
//            2 per-row (sum, sumsq) of final v -> rowpart[(b*NB+nb)*2M + {0,M} + row]
template <bool OUTBF16, int BIASMODE /*0 none,1 row,2 col*/, bool RELU,
          int RESMODE /*0,1=f32,2=bf16*/, int SCALEMODE, int ROWRED>
__global__ __launch_bounds__(256, 4) void mfma_gemm(const unsigned short* __restrict__ A,
                                                 const unsigned short* __restrict__ Bt,
                                                 const float* __restrict__ bias,
                                                 const void* __restrict__ resid,
                                                 void* __restrict__ C,
                                                 int K, int lda, int ldb, int ldc,
                                                 long strideA, long strideB, long strideC,
                                                 float scale,
                                                 const float* __restrict__ cscale, long strideCS,
                                                 float* __restrict__ rowpart) {
    __shared__ __align__(16) unsigned short As[2][128 * 32];
    __shared__ __align__(16) unsigned short Bs[2][128 * 32];
    __shared__ float rsS[2][128];
    __shared__ float rqS[2][128];
    int b  = blockIdx.z;
    int m0 = blockIdx.y * 128;
    int n0 = blockIdx.x * 128;
    const unsigned short* Ab = A  + (size_t)b * strideA;
    const unsigned short* Bb = Bt + (size_t)b * strideB;
    int t = threadIdx.x;
    int wv = t >> 6, L = t & 63;
    int wm = (wv >> 1) * 64, wn = (wv & 1) * 64;
    int lr = L & 15, lq = L >> 4;
    int srow = t >> 2;                       // staged row 0..63 (per half)
    int gchunk = (t & 3) ^ ((t >> 3) & 3);   // global 16B chunk, swizzle-matched
    int skof = gchunk * 8;                   // bf16 elem offset in k
    int swz = (lr >> 1) & 3;                 // read-side swizzle

    int aoff[4], boff[4];
#pragma unroll
    for (int i = 0; i < 4; ++i) {
        aoff[i] = (wm + i * 16 + lr) * 32 + ((lq ^ swz) * 8);
        boff[i] = (wn + i * 16 + lr) * 32 + ((lq ^ swz) * 8);
    }

    const unsigned short* gA0 = Ab + (size_t)(m0 + srow) * lda + skof;
    const unsigned short* gA1 = Ab + (size_t)(m0 + 64 + srow) * lda + skof;
    const unsigned short* gB0 = Bb + (size_t)(n0 + srow) * ldb + skof;
    const unsigned short* gB1 = Bb + (size_t)(n0 + 64 + srow) * ldb + skof;

    f32x4 acc[4][4] = {};
    int nIter = K >> 5;

    gload_lds16(gA0, &As[0][t * 8]);
    gload_lds16(gA1, &As[0][64 * 32 + t * 8]);
    gload_lds16(gB0, &Bs[0][t * 8]);
    gload_lds16(gB1, &Bs[0][64 * 32 + t * 8]);

    int p = 0;
    for (int i = 0; i < nIter; ++i) {
        __syncthreads();
        if (i + 1 < nIter) {
            int ko = (i + 1) << 5;
            gload_lds16(gA0 + ko, &As[p ^ 1][t * 8]);
            gload_lds16(gA1 + ko, &As[p ^ 1][64 * 32 + t * 8]);
            gload_lds16(gB0 + ko, &Bs[p ^ 1][t * 8]);
            gload_lds16(gB1 + ko, &Bs[p ^ 1][64 * 32 + t * 8]);
        }
        bf16x8 af[4], bfr[4];
#pragma unroll
        for (int j = 0; j < 4; ++j) af[j]  = *(const bf16x8*)&As[p][aoff[j]];
#pragma unroll
        for (int j = 0; j < 4; ++j) bfr[j] = *(const bf16x8*)&Bs[p][boff[j]];
#pragma unroll
        for (int ii = 0; ii < 4; ++ii)
#pragma unroll
            for (int jj = 0; jj < 4; ++jj)
                acc[ii][jj] = __builtin_amdgcn_mfma_f32_16x16x32_bf16(af[ii], bfr[jj], acc[ii][jj], 0, 0, 0);
        p ^= 1;
    }

    // epilogue: lane L, reg r -> row = lq*4 + r, col = lr (within 16x16 tile)
    float cs[4];
    if (SCALEMODE == 1) {
#pragma unroll
        for (int j = 0; j < 4; ++j)
            cs[j] = cscale[(size_t)b * strideCS + (n0 + wn + j * 16 + lr)];
    }
#pragma unroll
    for (int i = 0; i < 4; ++i) {
#pragma unroll
        for (int r = 0; r < 4; ++r) {
            int row = m0 + wm + i * 16 + lq * 4 + r;
            float brow = (BIASMODE == 1) ? bias[row] : 0.f;
            float s = 0.f, q2 = 0.f;
#pragma unroll
            for (int j = 0; j < 4; ++j) {
                int col = n0 + wn + j * 16 + lr;
                float v = acc[i][j][r] * scale;
                if (SCALEMODE == 1) v *= cs[j];
                if (BIASMODE == 1) v += brow;
                if (BIASMODE == 2) v += bias[col];
                if (RELU) v = fmaxf(v, 0.f);
                size_t off = (size_t)b * strideC + (size_t)row * ldc + col;
                if (RESMODE == 1) v += ((const float*)resid)[off];
                if (RESMODE == 2) v += bf2f(((const unsigned short*)resid)[off]);
                if (ROWRED == 1) v = __expf(v);
                if (ROWRED) { s += v; if (ROWRED == 2) q2 += v * v; }
                if (OUTBF16) ((unsigned short*)C)[off] = f2bf(v);
                else         ((float*)C)[off] = v;
            }
            if (ROWRED) {
#pragma unroll
                for (int m = 1; m <= 8; m <<= 1) {
                    s += __shfl_xor(s, m, 64);
                    if (ROWRED == 2) q2 += __shfl_xor(q2, m, 64);
                }
                if (lr == 0) {
                    int rl = wm + i * 16 + lq * 4 + r;
                    rsS[wv & 1][rl] = s;
                    if (ROWRED == 2) rqS[wv & 1][rl] = q2;
                }
            }
        }
    }
    if (ROWRED) {
        __syncthreads();
        if (t < 128) {
            int Mtot = gridDim.y << 7;
            size_t base = ((size_t)b * gridDim.x + blockIdx.x) *
                          (size_t)((ROWRED == 2 ? 2 : 1) * Mtot);
            rowpart[base + m0 + t] = rsS[0][t] + rsS[1][t];
            if (ROWRED == 2) rowpart[base + Mtot + m0 + t] = rqS[0][t] + rqS[1][t];
        }
    }
}

extern "C" void kernel_launch(void* const* d_in, const int* in_sizes, int n_in,
                              void* d_out, int out_size, void* d_ws, size_t ws_size,
                              hipStream_t stream) {
    const float* x     = (const float*)d_in[0];
    const float* bn1_g = (const float*)d_in[1];
    const float* bn1_b = (const float*)d_in[2];
    const float* W_qkv = (const float*)d_in[3];
    const float* b_qkv = (const float*)d_in[4];
    const float* bn2_g = (const float*)d_in[5];
    const float* bn2_b = (const float*)d_in[6];
    const float* W1    = (const float*)d_in[7];
    const float* b1    = (const float*)d_in[8];
    const float* W2    = (const float*)d_in[9];
    const float* b2    = (const float*)d_in[10];
    float* out = (float*)d_out;
    char* ws = (char*)d_ws;

    // workspace layout (bytes), ~170 MB total:
    unsigned short* hT    = (unsigned short*)(ws);                 // 32 MB (hT -> ybnT)
    unsigned short* qkT   = (unsigned short*)(ws + 33554432);      // 8 MB
    unsigned short* v     = (unsigned short*)(ws + 41943040);      // 32 MB (v -> y1T)
    unsigned short* betaT = (unsigned short*)(ws + 75497472);      // 64 MB (holds E = exp(beta))
    unsigned short* xr    = (unsigned short*)(ws + 142606336);     // 32 MB (bf16 xr)
    unsigned short* Wqkvb = (unsigned short*)(ws + 176160768);     // 640 KB
    unsigned short* W1b   = (unsigned short*)(ws + 176816128);     // 512 KB
    unsigned short* W2b   = (unsigned short*)(ws + 177340416);     // 512 KB
    float* stats = (float*)(ws + 177864704);                       // 2048 f32
    float* mean1 = stats,        *rstd1 = stats + 512;
    float* mean2 = stats + 1024, *rstd2 = stats + 1536;
    unsigned short* ybnT = hT;
    unsigned short* y1T  = v;
    // scratch aliased into hT region (hT dead between step 3b and step 8):
    float* rowpartQ  = (float*)(ws);             // [32][8][1024] = 1 MB
    float* invsum    = (float*)(ws + 1048576);   // [32][1024]    = 128 KB
    float* rowpartBN = (float*)(ws + 1179648);   // [32*8][2][512]= 1 MB

    const long sHT = (long)HWN * CC;    // 1024*512
    const long sQK = (long)HWN * 128;   // 1024*128
    const long sV  = (long)CC * HWN;    // 512*1024
    const long sBT = (long)HWN * HWN;   // 1024*1024

    // 0. weights -> bf16 (single launch)
    cvt3_kernel<<<(OO * CC + 2 * CC * CC) / 256, 256, 0, stream>>>(W_qkv, W1, W2, Wqkvb, W1b, W2b);
    // 1. bn1 stats (fp32 x)
    bn_stats_kernel<false><<<CC, 256, 0, stream>>>(x, mean1, rstd1);
    // 2. hT[b][s][c] = relu(bn1(x)) transposed, bf16
    bn_apply_t_kernel<true, false><<<dim3(16, 8, BB), 256, 0, stream>>>(x, mean1, rstd1, bn1_g, bn1_b, hT);
    // 3a. qkT[s][o'] = hT @ Wqk^T + b_qkv[o']   (M=1024, N=128, K=512), col bias
    mfma_gemm<true, 2, false, 0, 0, 0><<<dim3(1, 8, BB), 256, 0, stream>>>(
        hT, Wqkvb, b_qkv, nullptr, qkT, 512, 512, 512, 128, sHT, 0, sQK, 1.f, nullptr, 0, nullptr);
    // 3b. v[c][s] = Wv @ h + b_qkv[128+c]       (M=512, N=1024, K=512), row bias
    mfma_gemm<true, 1, false, 0, 0, 0><<<dim3(8, 4, BB), 256, 0, stream>>>(
        Wqkvb + 128 * 512, hT, b_qkv + 128, nullptr, v, 512, 512, 512, 1024, 0, sHT, sV, 1.f, nullptr, 0, nullptr);
    // 4. E[kj][qi] = exp((kT @ qT^T)/8)  (M=1024, N=1024, K=64); |beta|<~1 so no
    //    max-subtraction needed; per-row partial sums -> rowpartQ (softmax denom)
    mfma_gemm<true, 0, false, 0, 0, 1><<<dim3(8, 8, BB), 256, 0, stream>>>(
        qkT + 64, qkT, nullptr, nullptr, betaT, 64, 128, 128, 1024, sQK, sQK, sBT, 0.125f, nullptr, 0, rowpartQ);
    // 5. invsum[b][k] = 1 / sum_q E[k][q]
    reduce_invsum_kernel<<<128, 256, 0, stream>>>(rowpartQ, invsum);
    // 6. xr[c][s] = (v @ E^T)*invsum[s] + x, bf16 out (M=512, N=1024, K=1024),
    //    fp32 resid; fused bn2 partial (sum,sumsq) per row -> rowpartBN
    mfma_gemm<true, 0, false, 1, 1, 2><<<dim3(8, 4, BB), 256, 0, stream>>>(
        v, betaT, nullptr, x, xr, 1024, 1024, 1024, 1024, sV, sBT, sV, 1.f, invsum, 1024, rowpartBN);
    // 7. bn2 stats from fused partials
    reduce_bnstats_kernel<<<2, 256, 0, stream>>>(rowpartBN, mean2, rstd2);
    // 8. ybnT[s][c] = bn2(xr) transposed, bf16 (aliases hT)
    bn_apply_t_kernel<false, true><<<dim3(16, 8, BB), 256, 0, stream>>>(xr, mean2, rstd2, bn2_g, bn2_b, ybnT);
    // 9. y1T[s][o] = relu(ybnT @ W1^T + b1)     (M=1024, N=512, K=512), col bias (aliases v)
    mfma_gemm<true, 2, true, 0, 0, 0><<<dim3(4, 8, BB), 256, 0, stream>>>(
        ybnT, W1b, b1, nullptr, y1T, 512, 512, 512, 512, sHT, 0, sHT, 1.f, nullptr, 0, nullptr);
    // 10. out[c][s] = W2 @ y1T^T + b2 + xr(bf16) -> d_out fp32  (M=512, N=1024, K=512)
    mfma_gemm<false, 1, false, 2, 0, 0><<<dim3(8, 4, BB), 256, 0, stream>>>(
        W2b, y1T, b2, xr, out, 512, 512, 512, 1024, 0, sHT, sV, 1.f, nullptr, 0, nullptr);
}

// Round 2
// 376.628 us; speedup vs baseline: 1.1015x; 1.0449x over previous
//
#include <hip/hip_runtime.h>

#define BB 32
#define CC 512
#define HWN 1024
#define DD 64
#define OO 640  // 2*DD + CC

typedef short bf16x8 __attribute__((ext_vector_type(8)));
typedef float f32x4 __attribute__((ext_vector_type(4)));
typedef __attribute__((address_space(1))) const void gvoid;
typedef __attribute__((address_space(3))) void svoid;

__device__ __forceinline__ void gload_lds16(const void* g, void* l) {
    __builtin_amdgcn_global_load_lds((gvoid*)g, (svoid*)l, 16, 0, 0);
}

__device__ __forceinline__ unsigned short f2bf(float f) {
    unsigned int u = __float_as_uint(f);
    unsigned int r = u + 0x7FFFu + ((u >> 16) & 1u);  // RNE
    return (unsigned short)(r >> 16);
}
__device__ __forceinline__ float bf2f(unsigned short h) {
    return __uint_as_float(((unsigned int)h) << 16);
}

// ---------------- f32 -> bf16 convert, all 3 weight matrices in one launch ----
__global__ __launch_bounds__(256) void cvt3_kernel(const float* __restrict__ a,
                                                   const float* __restrict__ b,
                                                   const float* __restrict__ c,
                                                   unsigned short* __restrict__ oa,
                                                   unsigned short* __restrict__ ob,
                                                   unsigned short* __restrict__ oc) {
    const int n1 = OO * CC, n2 = CC * CC;
    int i = blockIdx.x * 256 + threadIdx.x;
    if (i < n1)            oa[i] = f2bf(a[i]);
    else if (i < n1 + n2)  ob[i - n1] = f2bf(b[i - n1]);
    else                   oc[i - n1 - n2] = f2bf(c[i - n1 - n2]);
}

// ---------------- BN stats: one block per channel (fp32 input, bn1 only) ------
template <bool INBF16>
__global__ __launch_bounds__(256) void bn_stats_kernel(const void* __restrict__ xv,
                                                       float* __restrict__ mean,
                                                       float* __restrict__ rstd) {
    int c = blockIdx.x;
    int t = threadIdx.x;
    float s = 0.f, s2 = 0.f;
    if (INBF16) {
        const unsigned int* x = (const unsigned int*)xv;  // 2 bf16 per uint
        for (int b = 0; b < BB; ++b) {
            const unsigned int* p = x + ((size_t)b * CC + c) * (HWN / 2);
#pragma unroll
            for (int i = 0; i < 2; ++i) {
                unsigned int w = p[t + i * 256];
                float v0 = bf2f((unsigned short)(w & 0xffffu));
                float v1 = bf2f((unsigned short)(w >> 16));
                s += v0 + v1; s2 += v0 * v0 + v1 * v1;
            }
        }
    } else {
        const float* x = (const float*)xv;
        for (int b = 0; b < BB; ++b) {
            const float* p = x + ((size_t)b * CC + c) * HWN;
#pragma unroll
            for (int i = 0; i < 4; ++i) {
                float v = p[t + i * 256];
                s += v; s2 += v * v;
            }
        }
    }
    for (int off = 32; off > 0; off >>= 1) {
        s  += __shfl_down(s,  off, 64);
        s2 += __shfl_down(s2, off, 64);
    }
    __shared__ float sh[4], sh2[4];
    int wave = t >> 6;
    if ((t & 63) == 0) { sh[wave] = s; sh2[wave] = s2; }
    __syncthreads();
    if (t == 0) {
        float ts = 0.f, ts2 = 0.f;
        for (int w = 0; w < 4; ++w) { ts += sh[w]; ts2 += sh2[w]; }
        const float invN = 1.f / (float)(BB * HWN);
        float m = ts * invN;
        float var = ts2 * invN - m * m;
        mean[c] = m;
        rstd[c] = rsqrtf(var + 1e-5f);
    }
}

// ------- BN apply + transpose: x[b][c][s] -> outT[b][s][c] bf16 (+relu) -------
template <bool RELU, bool INBF16>
__global__ __launch_bounds__(256) void bn_apply_t_kernel(const void* __restrict__ xv,
                                                         const float* __restrict__ mean,
                                                         const float* __restrict__ rstd,
                                                         const float* __restrict__ g,
                                                         const float* __restrict__ bta,
                                                         unsigned short* __restrict__ outT) {
    __shared__ float tile[64][65];
    int b  = blockIdx.z;
    int c0 = blockIdx.y * 64;
    int s0 = blockIdx.x * 64;
    int t = threadIdx.x;
    int sl = t & 63, grp = t >> 6;
#pragma unroll
    for (int i = 0; i < 16; ++i) {
        int cr = i * 4 + grp;
        int c = c0 + cr;
        float r  = rstd[c] * g[c];
        float sh = bta[c] - mean[c] * r;
        float xval;
        if (INBF16) {
            const unsigned short* xb = (const unsigned short*)xv;
            xval = bf2f(xb[((size_t)b * CC + c0 + cr) * HWN + s0 + sl]);
        } else {
            const float* xb = (const float*)xv;
            xval = xb[((size_t)b * CC + c0 + cr) * HWN + s0 + sl];
        }
        float v = fmaf(xval, r, sh);
        if (RELU) v = fmaxf(v, 0.f);
        tile[cr][sl] = v;
    }
    __syncthreads();
    unsigned short* ob = outT + ((size_t)b * HWN + s0) * CC + c0;
#pragma unroll
    for (int i = 0; i < 16; ++i) {
        int srow = i * 4 + grp;
        ob[(size_t)srow * CC + sl] = f2bf(tile[sl][srow]);
    }
}

// -------- reduce: bn2 mean/rstd from per-block partial (sum, sumsq) pairs ------
// part layout: [pair p = b*8+n][2][512] -> p*1024 + {0,512} + c
__global__ __launch_bounds__(256) void reduce_bnstats_kernel(const float* __restrict__ part,
                                                             float* __restrict__ mean,
                                                             float* __restrict__ rstd) {
    int c = blockIdx.x * 256 + threadIdx.x;  // 512
    float s = 0.f, s2 = 0.f;
    for (int p = 0; p < BB * 8; ++p) {
        s  += part[(size_t)p * 1024 + c];
        s2 += part[(size_t)p * 1024 + 512 + c];
    }
    const float invN = 1.f / (float)(BB * HWN);
    float m = s * invN;
    mean[c] = m;
    rstd[c] = rsqrtf(s2 * invN - m * m + 1e-5f);
}

// ---------------- Fused attention core: steps 4+5+6 in one kernel -------------
// Per block: all c (M=512) x 128 k-tokens; loop q in chunks of 64.
//   E-phase: beta[q,k] = (Q @ K^T)/8 via MFMA (A=Q rows q, B=K rows k),
//            E = exp(beta) -> bf16 -> Es LDS laid out as PV B-operand [k][q];
//            f32 row-sums accumulate softmax denom S[k] in registers.
//   PV-phase: acc[c][k] += v[c][q] * Es[k][q].
// Epilogue: acc * (1/S[k]) + x (fp32), bf16 store to xr, fused bn2 partials.
// grid (8, 1, 32), block 512 (8 waves: [wv>>1]=c-strip of 128, [wv&1]=k-half of 64).
__global__ __launch_bounds__(512, 2) void fused_pv_kernel(
        const unsigned short* __restrict__ qkTg,  // [b][1024][128] (q dims 0..63, k dims 64..127)
        const unsigned short* __restrict__ vg,    // [b][512][1024]
        const float* __restrict__ xg,             // [b][512][1024] fp32 resid
        unsigned short* __restrict__ xrg,         // [b][512][1024] bf16 out
        float* __restrict__ rowpart) {            // [b*8+nb][2][512] bn2 partials
    __shared__ __align__(16) unsigned short Ks[2 * 128 * 32];   // [kkd][k][32]
    __shared__ __align__(16) unsigned short Qs[2][2 * 64 * 32]; // [p][kkd][q][32]
    __shared__ __align__(16) unsigned short Vs[2 * 512 * 32];   // [kkq][c][32]
    __shared__ __align__(16) unsigned short Es[2 * 128 * 32];   // [kkq][k][32]
    __shared__ float sS[128];
    __shared__ float rsS[2][512];
    __shared__ float rqS[2][512];

    int b = blockIdx.z;
    int n0 = blockIdx.x * 128;
    const unsigned short* qk = qkTg + (size_t)b * (HWN * 128);
    const unsigned short* vb = vg + (size_t)b * ((size_t)CC * HWN);
    int t = threadIdx.x;
    int wv = t >> 6, L = t & 63;
    int lr = L & 15, lq = L >> 4;
    int swz = (lr >> 1) & 3;
    int cstrip = (wv >> 1) * 128;
    int khalf = (wv & 1) * 64;

    // prologue staging: K tile (1024 slots) + Q chunk 0 (512 slots)
#pragma unroll
    for (int is = 0; is < 2; ++is) {
        int idx = is * 512 + t;
        int kkd = idx >> 9, row = (idx >> 2) & 127, slot = idx & 3;
        int ch = slot ^ ((row >> 1) & 3);
        gload_lds16(qk + (size_t)(n0 + row) * 128 + 64 + kkd * 32 + ch * 8, &Ks[idx * 8]);
    }
    {
        int kkd = t >> 8, row = (t >> 2) & 63, slot = t & 3;
        int ch = slot ^ ((row >> 1) & 3);
        gload_lds16(qk + (size_t)row * 128 + kkd * 32 + ch * 8, &Qs[0][t * 8]);
    }

    f32x4 acc[8][4] = {};
    float S = 0.f;
    int p = 0;
    for (int i = 0; i < 16; ++i) {
        int q0 = i * 64;
        // stage V chunk i (safe: all waves passed barrier2 of prev iter)
#pragma unroll
        for (int is = 0; is < 8; ++is) {
            int idx = is * 512 + t;
            int kkq = idx >> 11, row = (idx >> 2) & 511, slot = idx & 3;
            int ch = slot ^ ((row >> 1) & 3);
            gload_lds16(vb + (size_t)row * HWN + q0 + kkq * 32 + ch * 8, &Vs[idx * 8]);
        }
        if (i + 1 < 16) {
            int kkd = t >> 8, row = (t >> 2) & 63, slot = t & 3;
            int ch = slot ^ ((row >> 1) & 3);
            gload_lds16(qk + (size_t)(q0 + 64 + row) * 128 + kkd * 32 + ch * 8,
                        &Qs[p ^ 1][t * 8]);
        }
        if (i == 0) __syncthreads();  // drain K, Q0 (V0/Q1 too; iter-0 only)

        // ---- E-phase: each wave computes q 0..63 x k [wv*16, wv*16+16) ----
        f32x4 eacc[4] = {};
#pragma unroll
        for (int kkd = 0; kkd < 2; ++kkd) {
            bf16x8 kb = *(const bf16x8*)&Ks[kkd * 4096 + (wv * 16 + lr) * 32 + ((lq ^ swz) * 8)];
#pragma unroll
            for (int qi = 0; qi < 4; ++qi) {
                bf16x8 qa = *(const bf16x8*)&Qs[p][kkd * 2048 + (qi * 16 + lr) * 32 + ((lq ^ swz) * 8)];
                eacc[qi] = __builtin_amdgcn_mfma_f32_16x16x32_bf16(qa, kb, eacc[qi], 0, 0, 0);
            }
        }
        // exp + pack to Es[k][q] (lane holds 4 q-contig values for k=wv*16+lr)
        float spart = 0.f;
#pragma unroll
        for (int qi = 0; qi < 4; ++qi) {
            float e0 = __expf(eacc[qi][0] * 0.125f);
            float e1 = __expf(eacc[qi][1] * 0.125f);
            float e2 = __expf(eacc[qi][2] * 0.125f);
            float e3 = __expf(eacc[qi][3] * 0.125f);
            spart += (e0 + e1) + (e2 + e3);
            unsigned int lo = (unsigned int)f2bf(e0) | ((unsigned int)f2bf(e1) << 16);
            unsigned int hi = (unsigned int)f2bf(e2) | ((unsigned int)f2bf(e3) << 16);
            int kkq = qi >> 1;
            int chunkE = (qi & 1) * 2 + (lq >> 1);
            int addr = kkq * 4096 + (wv * 16 + lr) * 32 + ((chunkE ^ swz) * 8) + (lq & 1) * 4;
            *(uint2*)&Es[addr] = make_uint2(lo, hi);
        }
        spart += __shfl_xor(spart, 16, 64);
        spart += __shfl_xor(spart, 32, 64);  // full sum over this wave's 64 q
        S += spart;
        __syncthreads();  // barrier1: Es visible; V[i], Q[i+1] drained (vmcnt0)

        // ---- PV-phase: acc[c][k] += v[c][q] * Es[k][q], 2 K-steps of 32 ----
#pragma unroll
        for (int kk = 0; kk < 2; ++kk) {
            bf16x8 af[8], bfj[4];
#pragma unroll
            for (int ii = 0; ii < 8; ++ii)
                af[ii] = *(const bf16x8*)&Vs[kk * 16384 + (cstrip + ii * 16 + lr) * 32 + ((lq ^ swz) * 8)];
#pragma unroll
            for (int j = 0; j < 4; ++j)
                bfj[j] = *(const bf16x8*)&Es[kk * 4096 + (khalf + j * 16 + lr) * 32 + ((lq ^ swz) * 8)];
#pragma unroll
            for (int ii = 0; ii < 8; ++ii)
#pragma unroll
                for (int j = 0; j < 4; ++j)
                    acc[ii][j] = __builtin_amdgcn_mfma_f32_16x16x32_bf16(af[ii], bfj[j], acc[ii][j], 0, 0, 0);
        }
        __syncthreads();  // barrier2: Es/Vs free for overwrite
        p ^= 1;
    }

    // softmax denominators -> LDS broadcast
    if (lq == 0) sS[wv * 16 + lr] = S;
    __syncthreads();
    float inv[4];
#pragma unroll
    for (int j = 0; j < 4; ++j) inv[j] = 1.f / sS[khalf + j * 16 + lr];

    const float* xb = xg + (size_t)b * ((size_t)CC * HWN);
    unsigned short* xrb = xrg + (size_t)b * ((size_t)CC * HWN);
#pragma unroll
    for (int ii = 0; ii < 8; ++ii) {
#pragma unroll
        for (int r = 0; r < 4; ++r) {
            int row = cstrip + ii * 16 + lq * 4 + r;
            float s = 0.f, q2 = 0.f;
#pragma unroll
            for (int j = 0; j < 4; ++j) {
                int col = n0 + khalf + j * 16 + lr;
                float val = acc[ii][j][r] * inv[j];
                size_t off = (size_t)row * HWN + col;
                val += xb[off];
                s += val; q2 += val * val;
                xrb[off] = f2bf(val);
            }
#pragma unroll
            for (int m = 1; m <= 8; m <<= 1) {
                s += __shfl_xor(s, m, 64);
                q2 += __shfl_xor(q2, m, 64);
            }
            if (lr == 0) { rsS[wv & 1][row] = s; rqS[wv & 1][row] = q2; }
        }
    }
    __syncthreads();
    {
        size_t base = ((size_t)b * 8 + blockIdx.x) * 1024;
        rowpart[base + t] = rsS[0][t] + rsS[1][t];
        rowpart[base + 512 + t] = rqS[0][t] + rqS[1][t];
    }
}

// ---------------- MFMA bf16 GEMM: C[b] = scale*(A @ Bt^T) (+bias)(+relu)(+resid)
template <bool OUTBF16, int BIASMODE /*0 none,1 row,2 col*/, bool RELU,
          int RESMODE /*0,1=f32,2=bf16*/>
__global__ __launch_bounds__(256, 4) void mfma_gemm(const unsigned short* __restrict__ A,
                                                 const unsigned short* __restrict__ Bt,
                                                 const float* __restrict__ bias,
                                                 const void* __restrict__ resid,
                                                 void* __restrict__ C,
                                                 int K, int lda, int ldb, int ldc,
                                                 long strideA, long strideB, long strideC,
                                                 float scale) {
    __shared__ __align__(16) unsigned short As[2][128 * 32];
    __shared__ __align__(16) unsigned short Bs[2][128 * 32];
    int b  = blockIdx.z;
    int m0 = blockIdx.y * 128;
    int n0 = blockIdx.x * 128;
    const unsigned short* Ab = A  + (size_t)b * strideA;
    const unsigned short* Bb = Bt + (size_t)b * strideB;
    int t = threadIdx.x;
    int wv = t >> 6, L = t & 63;
    int wm = (wv >> 1) * 64, wn = (wv & 1) * 64;
    int lr = L & 15, lq = L >> 4;
    int srow = t >> 2;                       // staged row 0..63 (per half)
    int gchunk = (t & 3) ^ ((t >> 3) & 3);   // global 16B chunk, swizzle-matched
    int skof = gchunk * 8;                   // bf16 elem offset in k
    int swz = (lr >> 1) & 3;                 // read-side swizzle

    int aoff[4], boff[4];
#pragma unroll
    for (int i = 0; i < 4; ++i) {
        aoff[i] = (wm + i * 16 + lr) * 32 + ((lq ^ swz) * 8);
        boff[i] = (wn + i * 16 + lr) * 32 + ((lq ^ swz) * 8);
    }

    const unsigned short* gA0 = Ab + (size_t)(m0 + srow) * lda + skof;
    const unsigned short* gA1 = Ab + (size_t)(m0 + 64 + srow) * lda + skof;
    const unsigned short* gB0 = Bb + (size_t)(n0 + srow) * ldb + skof;
    const unsigned short* gB1 = Bb + (size_t)(n0 + 64 + srow) * ldb + skof;

    f32x4 acc[4][4] = {};
    int nIter = K >> 5;

    gload_lds16(gA0, &As[0][t * 8]);
    gload_lds16(gA1, &As[0][64 * 32 + t * 8]);
    gload_lds16(gB0, &Bs[0][t * 8]);
    gload_lds16(gB1, &Bs[0][64 * 32 + t * 8]);

    int p = 0;
    for (int i = 0; i < nIter; ++i) {
        __syncthreads();
        if (i + 1 < nIter) {
            int ko = (i + 1) << 5;
            gload_lds16(gA0 + ko, &As[p ^ 1][t * 8]);
            gload_lds16(gA1 + ko, &As[p ^ 1][64 * 32 + t * 8]);
            gload_lds16(gB0 + ko, &Bs[p ^ 1][t * 8]);
            gload_lds16(gB1 + ko, &Bs[p ^ 1][64 * 32 + t * 8]);
        }
        bf16x8 af[4], bfr[4];
#pragma unroll
        for (int j = 0; j < 4; ++j) af[j]  = *(const bf16x8*)&As[p][aoff[j]];
#pragma unroll
        for (int j = 0; j < 4; ++j) bfr[j] = *(const bf16x8*)&Bs[p][boff[j]];
#pragma unroll
        for (int ii = 0; ii < 4; ++ii)
#pragma unroll
            for (int jj = 0; jj < 4; ++jj)
                acc[ii][jj] = __builtin_amdgcn_mfma_f32_16x16x32_bf16(af[ii], bfr[jj], acc[ii][jj], 0, 0, 0);
        p ^= 1;
    }

    // epilogue: lane L, reg r -> row = lq*4 + r, col = lr (within 16x16 tile)
#pragma unroll
    for (int i = 0; i < 4; ++i) {
#pragma unroll
        for (int r = 0; r < 4; ++r) {
            int row = m0 + wm + i * 16 + lq * 4 + r;
            float brow = (BIASMODE == 1) ? bias[row] : 0.f;
#pragma unroll
            for (int j = 0; j < 4; ++j) {
                int col = n0 + wn + j * 16 + lr;
                float v = acc[i][j][r] * scale;
                if (BIASMODE == 1) v += brow;
                if (BIASMODE == 2) v += bias[col];
                if (RELU) v = fmaxf(v, 0.f);
                size_t off = (size_t)b * strideC + (size_t)row * ldc + col;
                if (RESMODE == 1) v += ((const float*)resid)[off];
                if (RESMODE == 2) v += bf2f(((const unsigned short*)resid)[off]);
                if (OUTBF16) ((unsigned short*)C)[off] = f2bf(v);
                else         ((float*)C)[off] = v;
            }
        }
    }
}

extern "C" void kernel_launch(void* const* d_in, const int* in_sizes, int n_in,
                              void* d_out, int out_size, void* d_ws, size_t ws_size,
                              hipStream_t stream) {
    const float* x     = (const float*)d_in[0];
    const float* bn1_g = (const float*)d_in[1];
    const float* bn1_b = (const float*)d_in[2];
    const float* W_qkv = (const float*)d_in[3];
    const float* b_qkv = (const float*)d_in[4];
    const float* bn2_g = (const float*)d_in[5];
    const float* bn2_b = (const float*)d_in[6];
    const float* W1    = (const float*)d_in[7];
    const float* b1    = (const float*)d_in[8];
    const float* W2    = (const float*)d_in[9];
    const float* b2    = (const float*)d_in[10];
    float* out = (float*)d_out;
    char* ws = (char*)d_ws;

    // workspace layout (bytes):
    unsigned short* hT    = (unsigned short*)(ws);                 // 32 MB (hT -> ybnT)
    unsigned short* qkT   = (unsigned short*)(ws + 33554432);      // 8 MB
    unsigned short* v     = (unsigned short*)(ws + 41943040);      // 32 MB (v -> y1T)
    unsigned short* xr    = (unsigned short*)(ws + 142606336);     // 32 MB (bf16 xr)
    unsigned short* Wqkvb = (unsigned short*)(ws + 176160768);     // 640 KB
    unsigned short* W1b   = (unsigned short*)(ws + 176816128);     // 512 KB
    unsigned short* W2b   = (unsigned short*)(ws + 177340416);     // 512 KB
    float* stats = (float*)(ws + 177864704);                       // 2048 f32
    float* mean1 = stats,        *rstd1 = stats + 512;
    float* mean2 = stats + 1024, *rstd2 = stats + 1536;
    unsigned short* ybnT = hT;
    unsigned short* y1T  = v;
    // scratch aliased into hT region (hT dead between step 3b and step 8):
    float* rowpartBN = (float*)(ws + 1179648);   // [32*8][2][512] = 1 MB

    const long sHT = (long)HWN * CC;    // 1024*512
    const long sQK = (long)HWN * 128;   // 1024*128
    const long sV  = (long)CC * HWN;    // 512*1024

    // 0. weights -> bf16 (single launch)
    cvt3_kernel<<<(OO * CC + 2 * CC * CC) / 256, 256, 0, stream>>>(W_qkv, W1, W2, Wqkvb, W1b, W2b);
    // 1. bn1 stats (fp32 x)
    bn_stats_kernel<false><<<CC, 256, 0, stream>>>(x, mean1, rstd1);
    // 2. hT[b][s][c] = relu(bn1(x)) transposed, bf16
    bn_apply_t_kernel<true, false><<<dim3(16, 8, BB), 256, 0, stream>>>(x, mean1, rstd1, bn1_g, bn1_b, hT);
    // 3a. qkT[s][o'] = hT @ Wqk^T + b_qkv[o']   (M=1024, N=128, K=512), col bias
    mfma_gemm<true, 2, false, 0><<<dim3(1, 8, BB), 256, 0, stream>>>(
        hT, Wqkvb, b_qkv, nullptr, qkT, 512, 512, 512, 128, sHT, 0, sQK, 1.f);
    // 3b. v[c][s] = Wv @ h + b_qkv[128+c]       (M=512, N=1024, K=512), row bias
    mfma_gemm<true, 1, false, 0><<<dim3(8, 4, BB), 256, 0, stream>>>(
        Wqkvb + 128 * 512, hT, b_qkv + 128, nullptr, v, 512, 512, 512, 1024, 0, sHT, sV, 1.f);
    // 4-6. fused: E = exp(QK^T/8) on the fly, denom in-register, PV + x resid,
    //      bf16 xr out, fused bn2 partials
    fused_pv_kernel<<<dim3(8, 1, BB), 512, 0, stream>>>(qkT, v, x, xr, rowpartBN);
    // 7. bn2 stats from fused partials
    reduce_bnstats_kernel<<<2, 256, 0, stream>>>(rowpartBN, mean2, rstd2);
    // 8. ybnT[s][c] = bn2(xr) transposed, bf16 (aliases hT)
    bn_apply_t_kernel<false, true><<<dim3(16, 8, BB), 256, 0, stream>>>(xr, mean2, rstd2, bn2_g, bn2_b, ybnT);
    // 9. y1T[s][o] = relu(ybnT @ W1^T + b1)     (M=1024, N=512, K=512), col bias (aliases v)
    mfma_gemm<true, 2, true, 0><<<dim3(4, 8, BB), 256, 0, stream>>>(
        ybnT, W1b, b1, nullptr, y1T, 512, 512, 512, 512, sHT, 0, sHT, 1.f);
    // 10. out[c][s] = W2 @ y1T^T + b2 + xr(bf16) -> d_out fp32  (M=512, N=1024, K=512)
    mfma_gemm<false, 1, false, 2><<<dim3(8, 4, BB), 256, 0, stream>>>(
        W2b, y1T, b2, xr, out, 512, 512, 512, 1024, 0, sHT, sV, 1.f);
}

// Round 3
// 366.428 us; speedup vs baseline: 1.1322x; 1.0278x over previous
//
#include <hip/hip_runtime.h>

#define BB 32
#define CC 512
#define HWN 1024
#define DD 64
#define OO 640  // 2*DD + CC

typedef short bf16x8 __attribute__((ext_vector_type(8)));
typedef float f32x4 __attribute__((ext_vector_type(4)));
typedef __attribute__((address_space(1))) const void gvoid;
typedef __attribute__((address_space(3))) void svoid;

__device__ __forceinline__ void gload_lds16(const void* g, void* l) {
    __builtin_amdgcn_global_load_lds((gvoid*)g, (svoid*)l, 16, 0, 0);
}

__device__ __forceinline__ unsigned short f2bf(float f) {
    unsigned int u = __float_as_uint(f);
    unsigned int r = u + 0x7FFFu + ((u >> 16) & 1u);  // RNE
    return (unsigned short)(r >> 16);
}
__device__ __forceinline__ float bf2f(unsigned short h) {
    return __uint_as_float(((unsigned int)h) << 16);
}

// ---------------- f32 -> bf16 convert, all 3 weight matrices in one launch ----
__global__ __launch_bounds__(256) void cvt3_kernel(const float* __restrict__ a,
                                                   const float* __restrict__ b,
                                                   const float* __restrict__ c,
                                                   unsigned short* __restrict__ oa,
                                                   unsigned short* __restrict__ ob,
                                                   unsigned short* __restrict__ oc) {
    const int n1 = OO * CC, n2 = CC * CC;
    int i = blockIdx.x * 256 + threadIdx.x;
    if (i < n1)            oa[i] = f2bf(a[i]);
    else if (i < n1 + n2)  ob[i - n1] = f2bf(b[i - n1]);
    else                   oc[i - n1 - n2] = f2bf(c[i - n1 - n2]);
}

// ---------------- BN stats: one block per channel (fp32 input, bn1 only) ------
template <bool INBF16>
__global__ __launch_bounds__(256) void bn_stats_kernel(const void* __restrict__ xv,
                                                       float* __restrict__ mean,
                                                       float* __restrict__ rstd) {
    int c = blockIdx.x;
    int t = threadIdx.x;
    float s = 0.f, s2 = 0.f;
    if (INBF16) {
        const unsigned int* x = (const unsigned int*)xv;  // 2 bf16 per uint
        for (int b = 0; b < BB; ++b) {
            const unsigned int* p = x + ((size_t)b * CC + c) * (HWN / 2);
#pragma unroll
            for (int i = 0; i < 2; ++i) {
                unsigned int w = p[t + i * 256];
                float v0 = bf2f((unsigned short)(w & 0xffffu));
                float v1 = bf2f((unsigned short)(w >> 16));
                s += v0 + v1; s2 += v0 * v0 + v1 * v1;
            }
        }
    } else {
        const float* x = (const float*)xv;
        for (int b = 0; b < BB; ++b) {
            const float* p = x + ((size_t)b * CC + c) * HWN;
#pragma unroll
            for (int i = 0; i < 4; ++i) {
                float v = p[t + i * 256];
                s += v; s2 += v * v;
            }
        }
    }
    for (int off = 32; off > 0; off >>= 1) {
        s  += __shfl_down(s,  off, 64);
        s2 += __shfl_down(s2, off, 64);
    }
    __shared__ float sh[4], sh2[4];
    int wave = t >> 6;
    if ((t & 63) == 0) { sh[wave] = s; sh2[wave] = s2; }
    __syncthreads();
    if (t == 0) {
        float ts = 0.f, ts2 = 0.f;
        for (int w = 0; w < 4; ++w) { ts += sh[w]; ts2 += sh2[w]; }
        const float invN = 1.f / (float)(BB * HWN);
        float m = ts * invN;
        float var = ts2 * invN - m * m;
        mean[c] = m;
        rstd[c] = rsqrtf(var + 1e-5f);
    }
}

// ------- BN apply + transpose: x[b][c][s] -> outT[b][s][c] bf16 (+relu) -------
template <bool RELU, bool INBF16>
__global__ __launch_bounds__(256) void bn_apply_t_kernel(const void* __restrict__ xv,
                                                         const float* __restrict__ mean,
                                                         const float* __restrict__ rstd,
                                                         const float* __restrict__ g,
                                                         const float* __restrict__ bta,
                                                         unsigned short* __restrict__ outT) {
    __shared__ float tile[64][65];
    int b  = blockIdx.z;
    int c0 = blockIdx.y * 64;
    int s0 = blockIdx.x * 64;
    int t = threadIdx.x;
    int sl = t & 63, grp = t >> 6;
#pragma unroll
    for (int i = 0; i < 16; ++i) {
        int cr = i * 4 + grp;
        int c = c0 + cr;
        float r  = rstd[c] * g[c];
        float sh = bta[c] - mean[c] * r;
        float xval;
        if (INBF16) {
            const unsigned short* xb = (const unsigned short*)xv;
            xval = bf2f(xb[((size_t)b * CC + c0 + cr) * HWN + s0 + sl]);
        } else {
            const float* xb = (const float*)xv;
            xval = xb[((size_t)b * CC + c0 + cr) * HWN + s0 + sl];
        }
        float v = fmaf(xval, r, sh);
        if (RELU) v = fmaxf(v, 0.f);
        tile[cr][sl] = v;
    }
    __syncthreads();
    unsigned short* ob = outT + ((size_t)b * HWN + s0) * CC + c0;
#pragma unroll
    for (int i = 0; i < 16; ++i) {
        int srow = i * 4 + grp;
        ob[(size_t)srow * CC + sl] = f2bf(tile[sl][srow]);
    }
}

// -------- reduce: bn2 mean/rstd from per-block partial (sum, sumsq) pairs ------
// part layout: [pair p = b*8+n][2][512] -> p*1024 + {0,512} + c
__global__ __launch_bounds__(256) void reduce_bnstats_kernel(const float* __restrict__ part,
                                                             float* __restrict__ mean,
                                                             float* __restrict__ rstd) {
    int c = blockIdx.x * 256 + threadIdx.x;  // 512
    float s = 0.f, s2 = 0.f;
    for (int p = 0; p < BB * 8; ++p) {
        s  += part[(size_t)p * 1024 + c];
        s2 += part[(size_t)p * 1024 + 512 + c];
    }
    const float invN = 1.f / (float)(BB * HWN);
    float m = s * invN;
    mean[c] = m;
    rstd[c] = rsqrtf(s2 * invN - m * m + 1e-5f);
}

// ---------------- Fused attention core: steps 4+5+6 in one kernel -------------
// Per block: 256 c-rows (half) x 128 k-tokens; loop q in chunks of 64.
//   E-phase: beta[q,k] = (Q @ K^T)/8 via MFMA, E = exp(beta) -> bf16 -> Es LDS
//            (PV B-operand layout [k][q]); f32 row-sums accumulate denom S[k].
//   PV-phase: acc[c][k] += v[c][q] * Es[k][q].
// Epilogue: acc * (1/S[k]) + x (fp32), bf16 store to xr, fused bn2 partials.
// 512 blocks (16 x 32 grid), remapped so all 16 blocks of batch bb share an XCD
// (linear id = bb mod 32 => id mod 8 = bb mod 8) -> v[bb] chunk stays L2-hot.
// 512 thr = 8 waves: [wv>>1]=c-strip of 64, [wv&1]=k-half of 64.
// LDS 76.5 KB -> 2 blocks/CU.
__global__ __launch_bounds__(512, 4) void fused_pv_kernel(
        const unsigned short* __restrict__ qkTg,  // [b][1024][128] (q dims 0..63, k dims 64..127)
        const unsigned short* __restrict__ vg,    // [b][512][1024]
        const float* __restrict__ xg,             // [b][512][1024] fp32 resid
        unsigned short* __restrict__ xrg,         // [b][512][1024] bf16 out
        float* __restrict__ rowpart) {            // [b*8+nb][2][512] bn2 partials
    __shared__ __align__(16) unsigned short Ks[2 * 128 * 32];   // [kkd][k][32]
    __shared__ __align__(16) unsigned short Qs[2 * 64 * 32];    // [kkd][q][32] single-buf
    __shared__ __align__(16) unsigned short Vs[2 * 256 * 32];   // [kkq][c][32]
    __shared__ __align__(16) unsigned short Es[2 * 128 * 32];   // [kkq][k][32]
    __shared__ float sS[128];
    __shared__ float rsS[2][256];
    __shared__ float rqS[2][256];

    int lin = blockIdx.x + 16 * blockIdx.z;  // dispatch-linear (x fastest)
    int b  = lin & 31;                       // XCD = lin % 8 = b % 8 (heuristic)
    int nn = (lin >> 5) & 7;
    int ch = lin >> 8;
    int n0 = nn * 128;
    int c0 = ch * 256;
    const unsigned short* qk = qkTg + (size_t)b * (HWN * 128);
    const unsigned short* vb = vg + (size_t)b * ((size_t)CC * HWN);
    int t = threadIdx.x;
    int wv = t >> 6, L = t & 63;
    int lr = L & 15, lq = L >> 4;
    int swz = (lr >> 1) & 3;
    int cstrip = (wv >> 1) * 64;
    int khalf = (wv & 1) * 64;

    // prologue staging: K tile (1024 chunks) + Q chunk 0 (512 chunks)
#pragma unroll
    for (int is = 0; is < 2; ++is) {
        int idx = is * 512 + t;
        int kkd = idx >> 9, row = (idx >> 2) & 127, slot = idx & 3;
        int chk = slot ^ ((row >> 1) & 3);
        gload_lds16(qk + (size_t)(n0 + row) * 128 + 64 + kkd * 32 + chk * 8, &Ks[idx * 8]);
    }
    {
        int kkd = t >> 8, row = (t >> 2) & 63, slot = t & 3;
        int chk = slot ^ ((row >> 1) & 3);
        gload_lds16(qk + (size_t)row * 128 + kkd * 32 + chk * 8, &Qs[t * 8]);
    }

    f32x4 acc[4][4] = {};
    float S = 0.f;
    for (int i = 0; i < 16; ++i) {
        int q0 = i * 64;
        // stage V chunk i (rows c0..c0+255, q0..q0+63); covered by E-phase
#pragma unroll
        for (int is = 0; is < 4; ++is) {
            int idx = is * 512 + t;
            int kkq = idx >> 10, row = (idx >> 2) & 255, slot = idx & 3;
            int chk = slot ^ ((row >> 1) & 3);
            gload_lds16(vb + (size_t)(c0 + row) * HWN + q0 + kkq * 32 + chk * 8, &Vs[idx * 8]);
        }
        if (i == 0) __syncthreads();  // drain K, Q0, V0 (iter-0 only)

        // ---- E-phase: each wave computes q 0..63 x k [wv*16, wv*16+16) ----
        f32x4 eacc[4] = {};
#pragma unroll
        for (int kkd = 0; kkd < 2; ++kkd) {
            bf16x8 kb = *(const bf16x8*)&Ks[kkd * 4096 + (wv * 16 + lr) * 32 + ((lq ^ swz) * 8)];
#pragma unroll
            for (int qi = 0; qi < 4; ++qi) {
                bf16x8 qa = *(const bf16x8*)&Qs[kkd * 2048 + (qi * 16 + lr) * 32 + ((lq ^ swz) * 8)];
                eacc[qi] = __builtin_amdgcn_mfma_f32_16x16x32_bf16(qa, kb, eacc[qi], 0, 0, 0);
            }
        }
        // exp + pack to Es[k][q] (lane holds 4 q-contig values for k=wv*16+lr)
        float spart = 0.f;
#pragma unroll
        for (int qi = 0; qi < 4; ++qi) {
            float e0 = __expf(eacc[qi][0] * 0.125f);
            float e1 = __expf(eacc[qi][1] * 0.125f);
            float e2 = __expf(eacc[qi][2] * 0.125f);
            float e3 = __expf(eacc[qi][3] * 0.125f);
            spart += (e0 + e1) + (e2 + e3);
            unsigned int lo = (unsigned int)f2bf(e0) | ((unsigned int)f2bf(e1) << 16);
            unsigned int hi = (unsigned int)f2bf(e2) | ((unsigned int)f2bf(e3) << 16);
            int kkq = qi >> 1;
            int chunkE = (qi & 1) * 2 + (lq >> 1);
            int addr = kkq * 4096 + (wv * 16 + lr) * 32 + ((chunkE ^ swz) * 8) + (lq & 1) * 4;
            *(uint2*)&Es[addr] = make_uint2(lo, hi);
        }
        spart += __shfl_xor(spart, 16, 64);
        spart += __shfl_xor(spart, 32, 64);  // full sum over this wave's 64 q
        S += spart;
        __syncthreads();  // barrier1: Es visible; V[i] drained (vmcnt0)

        // stage Q chunk i+1 (single buffer: all waves done reading Qs for
        // iter i; drained by barrier2 under cover of PV MFMAs)
        if (i + 1 < 16) {
            int kkd = t >> 8, row = (t >> 2) & 63, slot = t & 3;
            int chk = slot ^ ((row >> 1) & 3);
            gload_lds16(qk + (size_t)(q0 + 64 + row) * 128 + kkd * 32 + chk * 8, &Qs[t * 8]);
        }

        // ---- PV-phase: acc[c][k] += v[c][q] * Es[k][q], 2 K-steps of 32 ----
#pragma unroll
        for (int kk = 0; kk < 2; ++kk) {
            bf16x8 af[4], bfj[4];
#pragma unroll
            for (int ii = 0; ii < 4; ++ii)
                af[ii] = *(const bf16x8*)&Vs[kk * 8192 + (cstrip + ii * 16 + lr) * 32 + ((lq ^ swz) * 8)];
#pragma unroll
            for (int j = 0; j < 4; ++j)
                bfj[j] = *(const bf16x8*)&Es[kk * 4096 + (khalf + j * 16 + lr) * 32 + ((lq ^ swz) * 8)];
#pragma unroll
            for (int ii = 0; ii < 4; ++ii)
#pragma unroll
                for (int j = 0; j < 4; ++j)
                    acc[ii][j] = __builtin_amdgcn_mfma_f32_16x16x32_bf16(af[ii], bfj[j], acc[ii][j], 0, 0, 0);
        }
        __syncthreads();  // barrier2: Es/Vs free; Q[i+1] drained
    }

    // softmax denominators -> LDS broadcast
    if (lq == 0) sS[wv * 16 + lr] = S;
    __syncthreads();
    float inv[4];
#pragma unroll
    for (int j = 0; j < 4; ++j) inv[j] = 1.f / sS[khalf + j * 16 + lr];

    const float* xb = xg + (size_t)b * ((size_t)CC * HWN);
    unsigned short* xrb = xrg + (size_t)b * ((size_t)CC * HWN);
#pragma unroll
    for (int ii = 0; ii < 4; ++ii) {
#pragma unroll
        for (int r = 0; r < 4; ++r) {
            int rloc = cstrip + ii * 16 + lq * 4 + r;   // 0..255
            int row = c0 + rloc;
            float s = 0.f, q2 = 0.f;
#pragma unroll
            for (int j = 0; j < 4; ++j) {
                int col = n0 + khalf + j * 16 + lr;
                float val = acc[ii][j][r] * inv[j];
                size_t off = (size_t)row * HWN + col;
                val += xb[off];
                s += val; q2 += val * val;
                xrb[off] = f2bf(val);
            }
#pragma unroll
            for (int m = 1; m <= 8; m <<= 1) {
                s += __shfl_xor(s, m, 64);
                q2 += __shfl_xor(q2, m, 64);
            }
            if (lr == 0) { rsS[wv & 1][rloc] = s; rqS[wv & 1][rloc] = q2; }
        }
    }
    __syncthreads();
    {
        size_t base = ((size_t)b * 8 + nn) * 1024;
        int rloc = t & 255;
        if (t < 256) rowpart[base + c0 + rloc]       = rsS[0][rloc] + rsS[1][rloc];
        else         rowpart[base + 512 + c0 + rloc] = rqS[0][rloc] + rqS[1][rloc];
    }
}

// ---------------- MFMA bf16 GEMM: C[b] = scale*(A @ Bt^T) (+bias)(+relu)(+resid)
template <bool OUTBF16, int BIASMODE /*0 none,1 row,2 col*/, bool RELU,
          int RESMODE /*0,1=f32,2=bf16*/>
__global__ __launch_bounds__(256, 4) void mfma_gemm(const unsigned short* __restrict__ A,
                                                 const unsigned short* __restrict__ Bt,
                                                 const float* __restrict__ bias,
                                                 const void* __restrict__ resid,
                                                 void* __restrict__ C,
                                                 int K, int lda, int ldb, int ldc,
                                                 long strideA, long strideB, long strideC,
                                                 float scale) {
    __shared__ __align__(16) unsigned short As[2][128 * 32];
    __shared__ __align__(16) unsigned short Bs[2][128 * 32];
    int b  = blockIdx.z;
    int m0 = blockIdx.y * 128;
    int n0 = blockIdx.x * 128;
    const unsigned short* Ab = A  + (size_t)b * strideA;
    const unsigned short* Bb = Bt + (size_t)b * strideB;
    int t = threadIdx.x;
    int wv = t >> 6, L = t & 63;
    int wm = (wv >> 1) * 64, wn = (wv & 1) * 64;
    int lr = L & 15, lq = L >> 4;
    int srow = t >> 2;                       // staged row 0..63 (per half)
    int gchunk = (t & 3) ^ ((t >> 3) & 3);   // global 16B chunk, swizzle-matched
    int skof = gchunk * 8;                   // bf16 elem offset in k
    int swz = (lr >> 1) & 3;                 // read-side swizzle

    int aoff[4], boff[4];
#pragma unroll
    for (int i = 0; i < 4; ++i) {
        aoff[i] = (wm + i * 16 + lr) * 32 + ((lq ^ swz) * 8);
        boff[i] = (wn + i * 16 + lr) * 32 + ((lq ^ swz) * 8);
    }

    const unsigned short* gA0 = Ab + (size_t)(m0 + srow) * lda + skof;
    const unsigned short* gA1 = Ab + (size_t)(m0 + 64 + srow) * lda + skof;
    const unsigned short* gB0 = Bb + (size_t)(n0 + srow) * ldb + skof;
    const unsigned short* gB1 = Bb + (size_t)(n0 + 64 + srow) * ldb + skof;

    f32x4 acc[4][4] = {};
    int nIter = K >> 5;

    gload_lds16(gA0, &As[0][t * 8]);
    gload_lds16(gA1, &As[0][64 * 32 + t * 8]);
    gload_lds16(gB0, &Bs[0][t * 8]);
    gload_lds16(gB1, &Bs[0][64 * 32 + t * 8]);

    int p = 0;
    for (int i = 0; i < nIter; ++i) {
        __syncthreads();
        if (i + 1 < nIter) {
            int ko = (i + 1) << 5;
            gload_lds16(gA0 + ko, &As[p ^ 1][t * 8]);
            gload_lds16(gA1 + ko, &As[p ^ 1][64 * 32 + t * 8]);
            gload_lds16(gB0 + ko, &Bs[p ^ 1][t * 8]);
            gload_lds16(gB1 + ko, &Bs[p ^ 1][64 * 32 + t * 8]);
        }
        bf16x8 af[4], bfr[4];
#pragma unroll
        for (int j = 0; j < 4; ++j) af[j]  = *(const bf16x8*)&As[p][aoff[j]];
#pragma unroll
        for (int j = 0; j < 4; ++j) bfr[j] = *(const bf16x8*)&Bs[p][boff[j]];
#pragma unroll
        for (int ii = 0; ii < 4; ++ii)
#pragma unroll
            for (int jj = 0; jj < 4; ++jj)
                acc[ii][jj] = __builtin_amdgcn_mfma_f32_16x16x32_bf16(af[ii], bfr[jj], acc[ii][jj], 0, 0, 0);
        p ^= 1;
    }

    // epilogue: lane L, reg r -> row = lq*4 + r, col = lr (within 16x16 tile)
#pragma unroll
    for (int i = 0; i < 4; ++i) {
#pragma unroll
        for (int r = 0; r < 4; ++r) {
            int row = m0 + wm + i * 16 + lq * 4 + r;
            float brow = (BIASMODE == 1) ? bias[row] : 0.f;
#pragma unroll
            for (int j = 0; j < 4; ++j) {
                int col = n0 + wn + j * 16 + lr;
                float v = acc[i][j][r] * scale;
                if (BIASMODE == 1) v += brow;
                if (BIASMODE == 2) v += bias[col];
                if (RELU) v = fmaxf(v, 0.f);
                size_t off = (size_t)b * strideC + (size_t)row * ldc + col;
                if (RESMODE == 1) v += ((const float*)resid)[off];
                if (RESMODE == 2) v += bf2f(((const unsigned short*)resid)[off]);
                if (OUTBF16) ((unsigned short*)C)[off] = f2bf(v);
                else         ((float*)C)[off] = v;
            }
        }
    }
}

extern "C" void kernel_launch(void* const* d_in, const int* in_sizes, int n_in,
                              void* d_out, int out_size, void* d_ws, size_t ws_size,
                              hipStream_t stream) {
    const float* x     = (const float*)d_in[0];
    const float* bn1_g = (const float*)d_in[1];
    const float* bn1_b = (const float*)d_in[2];
    const float* W_qkv = (const float*)d_in[3];
    const float* b_qkv = (const float*)d_in[4];
    const float* bn2_g = (const float*)d_in[5];
    const float* bn2_b = (const float*)d_in[6];
    const float* W1    = (const float*)d_in[7];
    const float* b1    = (const float*)d_in[8];
    const float* W2    = (const float*)d_in[9];
    const float* b2    = (const float*)d_in[10];
    float* out = (float*)d_out;
    char* ws = (char*)d_ws;

    // workspace layout (bytes):
    unsigned short* hT    = (unsigned short*)(ws);                 // 32 MB (hT -> ybnT)
    unsigned short* qkT   = (unsigned short*)(ws + 33554432);      // 8 MB
    unsigned short* v     = (unsigned short*)(ws + 41943040);      // 32 MB (v -> y1T)
    unsigned short* xr    = (unsigned short*)(ws + 142606336);     // 32 MB (bf16 xr)
    unsigned short* Wqkvb = (unsigned short*)(ws + 176160768);     // 640 KB
    unsigned short* W1b   = (unsigned short*)(ws + 176816128);     // 512 KB
    unsigned short* W2b   = (unsigned short*)(ws + 177340416);     // 512 KB
    float* stats = (float*)(ws + 177864704);                       // 2048 f32
    float* mean1 = stats,        *rstd1 = stats + 512;
    float* mean2 = stats + 1024, *rstd2 = stats + 1536;
    unsigned short* ybnT = hT;
    unsigned short* y1T  = v;
    // scratch aliased into hT region (hT dead between step 3b and step 8):
    float* rowpartBN = (float*)(ws + 1179648);   // [32*8][2][512] = 1 MB

    const long sHT = (long)HWN * CC;    // 1024*512
    const long sQK = (long)HWN * 128;   // 1024*128
    const long sV  = (long)CC * HWN;    // 512*1024

    // 0. weights -> bf16 (single launch)
    cvt3_kernel<<<(OO * CC + 2 * CC * CC) / 256, 256, 0, stream>>>(W_qkv, W1, W2, Wqkvb, W1b, W2b);
    // 1. bn1 stats (fp32 x)
    bn_stats_kernel<false><<<CC, 256, 0, stream>>>(x, mean1, rstd1);
    // 2. hT[b][s][c] = relu(bn1(x)) transposed, bf16
    bn_apply_t_kernel<true, false><<<dim3(16, 8, BB), 256, 0, stream>>>(x, mean1, rstd1, bn1_g, bn1_b, hT);
    // 3a. qkT[s][o'] = hT @ Wqk^T + b_qkv[o']   (M=1024, N=128, K=512), col bias
    mfma_gemm<true, 2, false, 0><<<dim3(1, 8, BB), 256, 0, stream>>>(
        hT, Wqkvb, b_qkv, nullptr, qkT, 512, 512, 512, 128, sHT, 0, sQK, 1.f);
    // 3b. v[c][s] = Wv @ h + b_qkv[128+c]       (M=512, N=1024, K=512), row bias
    mfma_gemm<true, 1, false, 0><<<dim3(8, 4, BB), 256, 0, stream>>>(
        Wqkvb + 128 * 512, hT, b_qkv + 128, nullptr, v, 512, 512, 512, 1024, 0, sHT, sV, 1.f);
    // 4-6. fused: E = exp(QK^T/8) on the fly, denom in-register, PV + x resid,
    //      bf16 xr out, fused bn2 partials; c-split (2 blocks/CU) + XCD remap
    fused_pv_kernel<<<dim3(16, 1, BB), 512, 0, stream>>>(qkT, v, x, xr, rowpartBN);
    // 7. bn2 stats from fused partials
    reduce_bnstats_kernel<<<2, 256, 0, stream>>>(rowpartBN, mean2, rstd2);
    // 8. ybnT[s][c] = bn2(xr) transposed, bf16 (aliases hT)
    bn_apply_t_kernel<false, true><<<dim3(16, 8, BB), 256, 0, stream>>>(xr, mean2, rstd2, bn2_g, bn2_b, ybnT);
    // 9. y1T[s][o] = relu(ybnT @ W1^T + b1)     (M=1024, N=512, K=512), col bias (aliases v)
    mfma_gemm<true, 2, true, 0><<<dim3(4, 8, BB), 256, 0, stream>>>(
        ybnT, W1b, b1, nullptr, y1T, 512, 512, 512, 512, sHT, 0, sHT, 1.f);
    // 10. out[c][s] = W2 @ y1T^T + b2 + xr(bf16) -> d_out fp32  (M=512, N=1024, K=512)
    mfma_gemm<false, 1, false, 2><<<dim3(8, 4, BB), 256, 0, stream>>>(
        W2b, y1T, b2, xr, out, 512, 512, 512, 1024, 0, sHT, sV, 1.f);
}